// Round 3
// baseline (574.659 us; speedup 1.0000x reference)
//
#include <hip/hip_runtime.h>
#include <hip/hip_bf16.h>

// S = (Q K^T)/32 * mask (multiplicative), attn = softmax(S), ctx = attn * K.
// d_out = ctx (8*2048*1024 f32) ++ attn (8*2048*2048 f32).
// R5: (1) GEMM staging rescheduled so every vmcnt waits on loads issued 4-6
// phases earlier (was 2); T-loop unrolled x2 for compile-time LDS parity.
// (2) kt_kernel: LDS-tiled transpose -> coalesced stores. (3) softmax: one
// wave per row, barrier-free.

typedef __attribute__((ext_vector_type(8))) short bf16x8;
typedef __attribute__((ext_vector_type(4))) float f32x4;
typedef __attribute__((ext_vector_type(4))) unsigned u32x4;
typedef __attribute__((ext_vector_type(2))) unsigned u32x2;

constexpr int BATCH = 8;
constexpr int LQ    = 2048;
constexpr int LKK   = 2048;
constexpr int DH    = 1024;
constexpr float SCALE = 0.03125f;   // 1/sqrt(1024)

#define GAS(p) ((const __attribute__((address_space(1))) void*)(p))
#define LAS(p) ((__attribute__((address_space(3))) void*)(p))

// 32-bit LDS byte offset of a generic pointer into __shared__
__device__ __forceinline__ unsigned lds_addr(const unsigned short* p) {
    return (unsigned)(unsigned long long)
        (const __attribute__((address_space(3))) unsigned short*)p;
}

// opaque LDS read (rule 18: caller waits lgkmcnt + sched_barrier(0) before use)
__device__ __forceinline__ bf16x8 dsr_b128(unsigned off) {
    bf16x8 r;
    asm volatile("ds_read_b128 %0, %1" : "=v"(r) : "v"(off));
    return r;
}

// round-half-up fp32->bf16 pair pack (2 adds + v_perm)
__device__ __forceinline__ unsigned pack_bf16x2(float x0, float x1) {
    unsigned a = __builtin_bit_cast(unsigned, x0) + 0x8000u;
    unsigned b = __builtin_bit_cast(unsigned, x1) + 0x8000u;
    return __builtin_amdgcn_perm(b, a, 0x07060302u);  // mem order: x0.hi16, x1.hi16
}

// ---------------- prep: Q,K fp32 -> bf16 (row-major, same layout) ----------------
__global__ __launch_bounds__(256)
void cvt_kernel(const float* __restrict__ Q, const float* __restrict__ K,
                unsigned short* __restrict__ Qb, unsigned short* __restrict__ Kb) {
    const int bid = blockIdx.x;
    const float* src; unsigned short* dst; size_t off;
    if (bid < 4096) { src = Q; dst = Qb; off = (size_t)bid * 4096; }
    else            { src = K; dst = Kb; off = (size_t)(bid - 4096) * 4096; }
    off += (size_t)threadIdx.x * 16;
    const f32x4 a = *(const f32x4*)(src + off);
    const f32x4 b = *(const f32x4*)(src + off + 4);
    const f32x4 c = *(const f32x4*)(src + off + 8);
    const f32x4 d = *(const f32x4*)(src + off + 12);
    u32x4 v0, v1;
    v0[0] = pack_bf16x2(a[0], a[1]); v0[1] = pack_bf16x2(a[2], a[3]);
    v0[2] = pack_bf16x2(b[0], b[1]); v0[3] = pack_bf16x2(b[2], b[3]);
    v1[0] = pack_bf16x2(c[0], c[1]); v1[1] = pack_bf16x2(c[2], c[3]);
    v1[2] = pack_bf16x2(d[0], d[1]); v1[3] = pack_bf16x2(d[2], d[3]);
    *(u32x4*)(dst + off)     = v0;
    *(u32x4*)(dst + off + 8) = v1;
}

// ---------------- prep: K fp32 -> K^T bf16 via LDS (coalesced stores) -------------
// Old version stored 8 B at 16 KB stride (uncoalesced, ~8x write amplification).
// Now: register 4x4 transpose -> LDS tile [64 d][64 k] (stride 68) -> coalesced
// 32 B/thread stores (128 B contiguous per d-row quad).
__global__ __launch_bounds__(256)
void kt_kernel(const float* __restrict__ K, unsigned short* __restrict__ KT) {
    __shared__ unsigned short T[64 * 68];
    const int b  = blockIdx.z;
    const int k0 = blockIdx.y * 64;
    const int d0 = blockIdx.x * 64;
    const int t  = threadIdx.x;
    const int k4 = (t >> 4) * 4;
    const int d4 = (t & 15) * 4;
    f32x4 rk[4];
    const float* Kp = K + ((size_t)b * LKK + k0 + k4) * DH + d0 + d4;
#pragma unroll
    for (int j = 0; j < 4; ++j) rk[j] = *(const f32x4*)(Kp + (size_t)j * DH);
#pragma unroll
    for (int c = 0; c < 4; ++c) {
        u32x2 w;
        w[0] = pack_bf16x2(rk[0][c], rk[1][c]);
        w[1] = pack_bf16x2(rk[2][c], rk[3][c]);
        *(u32x2*)&T[(d4 + c) * 68 + k4] = w;   // byte addr 136*(d4+c)+8*(t>>4): 8B-aligned
    }
    __syncthreads();
    const int d  = t >> 2;
    const int kc = (t & 3) * 16;
    u32x2 a0 = *(const u32x2*)&T[d * 68 + kc];
    u32x2 a1 = *(const u32x2*)&T[d * 68 + kc + 4];
    u32x2 a2 = *(const u32x2*)&T[d * 68 + kc + 8];
    u32x2 a3 = *(const u32x2*)&T[d * 68 + kc + 12];
    unsigned short* dst = KT + ((size_t)b * DH + d0 + d) * LKK + k0 + kc;
    u32x4 w0; w0[0] = a0[0]; w0[1] = a0[1]; w0[2] = a1[0]; w0[3] = a1[1];
    u32x4 w1; w1[0] = a2[0]; w1[1] = a2[1]; w1[2] = a3[0]; w1[3] = a3[1];
    *(u32x4*)dst       = w0;
    *(u32x4*)(dst + 8) = w1;
}

// ================= 256x256 BK=64 pipelined mainloop (R5 schedule) ==================
// LDS per matrix: [2 parity][2 khalf][256 rows][32 k bf16] = 64 KiB (A) + 64 KiB (B).
// Half index I: tile = I>>2, h = I&3 (0:A-kh0, 1:B-kh0, 2:A-kh1, 3:B-kh1).
// Tile T consumes halves 4T..4T+3 (kh0 at q=0,1; kh1 at q=2,3).
// Stage schedule (issue -> wait slack 4-6 phases, was 2):
//   q=0: stage 4T+6 (A-kh1 of T+1; region (par^1,kh1) last read T-1 q=3 -> legal)
//   q=1: stage 4T+7 (B-kh1 of T+1); after MFMA: vmcnt(8) -> halves 4T+2,3 landed
//        (kh1 of THIS tile, issued at T-1 q=0,1: 4-5 phases earlier)
//   q=2: stage 4T+8, 4T+9 (A/B-kh0 of T+2; region (par,kh0) last read q=1 -> legal)
//   q=3: after MFMA: vmcnt(8) -> halves 4T+4,5 landed (kh0 of T+1, issued T-1 q=2:
//        5-6 phases earlier)
// Steady state: 12 instrs outstanding at each wait, retire 4 -> vmcnt(8).
// Tail: T==NT-2 q=3 -> vmcnt(4); T==NT-1 q=1 -> vmcnt(0); stages guarded I<4NT.
// Prologue: stage halves 0..5, vmcnt(8) (halves 0,1 landed; 2,3 by T0-q1 wait).
// WAR: every overwrite issues >=1 phase-end barrier after the region's last read;
// all waves drain their ds_reads (lgkmcnt(0)) before each phase-end barrier.
template<int LDA, int LDB, int NT>
__device__ __forceinline__ void gemm8_mainloop(
    const unsigned short* __restrict__ Ab,
    const unsigned short* __restrict__ Bb,
    unsigned short* lA, unsigned short* lB,
    f32x4 (&acc)[8][4])
{
    const int tid  = threadIdx.x;
    const int lane = tid & 63;
    const int wid  = tid >> 6;
    const int wm   = (wid & 1) * 128;
    const int wn   = (wid >> 1) * 64;
    const int lrow = lane & 15;
    const int quad = lane >> 4;
    const int slotsw = (quad ^ ((lrow >> 1) & 3)) * 8;     // swizzled read slot (shorts)

    const int srow0 = wid * 32 + (lane >> 2);
    const int srow1 = srow0 + 16;
    const int sc    = ((lane & 3) ^ ((lane >> 3) & 3)) * 8; // pre-swizzled source col

    auto stage = [&](int I) {
        if (I >= 4 * NT) return;
        const int tile = I >> 2;
        const int h    = I & 3;
        const int kh   = h >> 1;
        const int kb   = tile * 64 + kh * 32 + sc;
        const unsigned short* s = (h & 1) ? Bb : Ab;
        const int ld            = (h & 1) ? LDB : LDA;
        unsigned short* d = ((h & 1) ? lB : lA)
                          + (tile & 1) * 16384 + kh * 8192 + wid * 1024;
        __builtin_amdgcn_global_load_lds(GAS(s + (size_t)srow0 * ld + kb), LAS(d),       16, 0, 0);
        __builtin_amdgcn_global_load_lds(GAS(s + (size_t)srow1 * ld + kb), LAS(d + 512), 16, 0, 0);
    };

#pragma unroll
    for (int i = 0; i < 8; ++i)
#pragma unroll
        for (int j = 0; j < 4; ++j) acc[i][j] = (f32x4){0.f, 0.f, 0.f, 0.f};

    // prologue: tile0 complete + tile1 kh0 in flight (12 instrs)
#pragma unroll
    for (int I = 0; I < 6; ++I) stage(I);
    asm volatile("s_waitcnt vmcnt(8)" ::: "memory");   // halves 0,1 landed
    __builtin_amdgcn_s_barrier();

    auto tilebody = [&](int T, int par) {
        bf16x8 bfr[4];
#pragma unroll
        for (int q = 0; q < 4; ++q) {
            const int kh = (q >> 1) * 8192;
            const int mh = (q & 1) * 4;
            if ((q & 1) == 0) {
#pragma unroll
                for (int nf = 0; nf < 4; ++nf)
                    bfr[nf] = dsr_b128(lds_addr(&lB[par + kh + (wn + nf * 16 + lrow) * 32 + slotsw]));
            }
            bf16x8 af[4];
#pragma unroll
            for (int mf = 0; mf < 4; ++mf)
                af[mf] = dsr_b128(lds_addr(&lA[par + kh + (wm + (mh + mf) * 16 + lrow) * 32 + slotsw]));

            if (q == 0)      stage(4 * T + 6);
            else if (q == 1) stage(4 * T + 7);
            else if (q == 2) { stage(4 * T + 8); stage(4 * T + 9); }

            __builtin_amdgcn_s_barrier();
            asm volatile("s_waitcnt lgkmcnt(0)" ::: "memory");
            __builtin_amdgcn_sched_barrier(0);
            __builtin_amdgcn_s_setprio(1);
#pragma unroll
            for (int mf = 0; mf < 4; ++mf)
#pragma unroll
                for (int nf = 0; nf < 4; ++nf)
                    acc[mh + mf][nf] = __builtin_amdgcn_mfma_f32_16x16x32_bf16(
                        af[mf], bfr[nf], acc[mh + mf][nf], 0, 0, 0);
            __builtin_amdgcn_s_setprio(0);
            if (q == 1) {
                if (T < NT - 1)      asm volatile("s_waitcnt vmcnt(8)" ::: "memory");
                else                 asm volatile("s_waitcnt vmcnt(0)" ::: "memory");
            } else if (q == 3) {
                if (T < NT - 2)      asm volatile("s_waitcnt vmcnt(8)" ::: "memory");
                else if (T == NT - 2) asm volatile("s_waitcnt vmcnt(4)" ::: "memory");
            }
            __builtin_amdgcn_s_barrier();
        }
    };

    for (int T = 0; T < NT; T += 2) {   // NT even; compile-time LDS parity
        tilebody(T,     0);
        tilebody(T + 1, 16384);
    }
}

// ---------------- GEMM1: S[b,q,n] = (Qb[q,:] . Kb[n,:]) * SCALE * M ----------------
__global__ __launch_bounds__(512, 2)
void qk8(const unsigned short* __restrict__ Qb, const unsigned short* __restrict__ Kb,
         const float* __restrict__ M, float* __restrict__ S) {
    __shared__ __align__(16) unsigned short lA[32768];
    __shared__ __align__(16) unsigned short lB[32768];

    // 512 blocks: XCD-bijective swizzle (512 % 8 == 0); each XCD chunk = one batch.
    const int l   = blockIdx.x;
    const int swz = (l & 7) * 64 + (l >> 3);
    const int b   = swz >> 6;
    const int my  = (swz >> 3) & 7;
    const int nx  = swz & 7;
    const int q0  = my * 256;
    const int n0  = nx * 256;

    const unsigned short* Ap = Qb + ((size_t)b * LQ  + q0) * DH;
    const unsigned short* Bp = Kb + ((size_t)b * LKK + n0) * DH;

    f32x4 acc[8][4];
    gemm8_mainloop<DH, DH, DH / 64>(Ap, Bp, lA, lB, acc);

    const int lane = threadIdx.x & 63;
    const int wid  = threadIdx.x >> 6;
    const int wm   = (wid & 1) * 128;
    const int wn   = (wid >> 1) * 64;
    const int lrow = lane & 15;
    const int quad = lane >> 4;

    // C/D layout: col = lane&15, row = quad*4 + r (m89/m91)
    const size_t base = (size_t)b * LQ * LKK;
#pragma unroll
    for (int mf = 0; mf < 8; ++mf) {
#pragma unroll
        for (int r = 0; r < 4; ++r) {
            const int row = q0 + wm + mf * 16 + quad * 4 + r;
            const size_t rb = base + (size_t)row * LKK;
#pragma unroll
            for (int nf = 0; nf < 4; ++nf) {
                const int col = n0 + wn + nf * 16 + lrow;
                S[rb + col] = acc[mf][nf][r] * SCALE * M[rb + col];
            }
        }
    }
}

// ---------------- softmax: one wave per row, barrier-free; bf16 copy for pk --------
__global__ __launch_bounds__(256)
void softmax_kernel(float* __restrict__ A, unsigned short* __restrict__ ab) {
    const int row  = blockIdx.x * 4 + (threadIdx.x >> 6);
    const int lane = threadIdx.x & 63;
    float* p = A + (size_t)row * LKK;

    f32x4 v[8];
#pragma unroll
    for (int i = 0; i < 8; ++i) v[i] = *(const f32x4*)(p + i * 256 + lane * 4);

    float m = v[0][0];
#pragma unroll
    for (int i = 0; i < 8; ++i)
#pragma unroll
        for (int j = 0; j < 4; ++j) m = fmaxf(m, v[i][j]);
#pragma unroll
    for (int o = 32; o >= 1; o >>= 1) m = fmaxf(m, __shfl_xor(m, o, 64));

    float s = 0.f;
#pragma unroll
    for (int i = 0; i < 8; ++i)
#pragma unroll
        for (int j = 0; j < 4; ++j) { v[i][j] = __expf(v[i][j] - m); s += v[i][j]; }
#pragma unroll
    for (int o = 32; o >= 1; o >>= 1) s += __shfl_xor(s, o, 64);
    const float inv = 1.f / s;

#pragma unroll
    for (int i = 0; i < 8; ++i) {
#pragma unroll
        for (int j = 0; j < 4; ++j) v[i][j] *= inv;
        *(f32x4*)(p + i * 256 + lane * 4) = v[i];
    }

    if (ab) {
        unsigned short* q = ab + (size_t)row * LKK;
#pragma unroll
        for (int i = 0; i < 8; ++i) {
            u32x2 w;
            w[0] = pack_bf16x2(v[i][0], v[i][1]);
            w[1] = pack_bf16x2(v[i][2], v[i][3]);
            *(u32x2*)(q + i * 256 + lane * 4) = w;
        }
    }
}

// ---------------- GEMM2: ctx = attn_bf * KT_bf (both pre-packed bf16) ---------
__global__ __launch_bounds__(512, 2)
void pk8(const unsigned short* __restrict__ Pb, const unsigned short* __restrict__ KT,
         float* __restrict__ C) {
    __shared__ __align__(16) unsigned short lA[32768];
    __shared__ __align__(16) unsigned short lB[32768];

    // 256 blocks: b(8) x my(8) x nx(4), XCD-bijective swizzle (256 % 8 == 0).
    const int l   = blockIdx.x;
    const int swz = (l & 7) * 32 + (l >> 3);
    const int b   = swz >> 5;
    const int my  = (swz >> 2) & 7;
    const int nx  = swz & 3;
    const int q0  = my * 256;
    const int n0  = nx * 256;   // d offset

    const unsigned short* Ap = Pb + ((size_t)b * LQ + q0) * LKK;
    const unsigned short* Bp = KT + ((size_t)b * DH + n0) * LKK;

    f32x4 acc[8][4];
    gemm8_mainloop<LKK, LKK, LKK / 64>(Ap, Bp, lA, lB, acc);

    const int lane = threadIdx.x & 63;
    const int wid  = threadIdx.x >> 6;
    const int wm   = (wid & 1) * 128;
    const int wn   = (wid >> 1) * 64;
    const int lrow = lane & 15;
    const int quad = lane >> 4;

    const size_t cb = (size_t)b * LQ * DH;
#pragma unroll
    for (int mf = 0; mf < 8; ++mf) {
#pragma unroll
        for (int r = 0; r < 4; ++r) {
            const int row = q0 + wm + mf * 16 + quad * 4 + r;
            const size_t rbase = cb + (size_t)row * DH;
#pragma unroll
            for (int nf = 0; nf < 4; ++nf)
                C[rbase + n0 + wn + nf * 16 + lrow] = acc[mf][nf][r];
        }
    }
}

// ---------------- GEMM2 fallback (128^2 2-phase): inline fp32->bf16 ----------------
constexpr int BM = 128, BN = 128, TK = 32;
constexpr int LDSS = 40;
__global__ __launch_bounds__(256, 2)
void pk_kernel(const float* __restrict__ P, const float* __restrict__ K,
               float* __restrict__ C) {
    __shared__ unsigned short lA[BM * LDSS];
    __shared__ unsigned short lB[BN * LDSS];

    const int b  = blockIdx.z;
    const int q0 = blockIdx.y * BM;
    const int n0 = blockIdx.x * BN;
    const float* Pp = P + (size_t)b * LQ * LKK + (size_t)q0 * LKK;
    const float* Kb = K + (size_t)b * LKK * DH;

    const int tid  = threadIdx.x;
    const int lane = tid & 63;
    const int wid  = tid >> 6;
    const int wm   = (wid & 1) * 64;
    const int wn   = (wid >> 1) * 64;
    const int lrow = lane & 15;
    const int quad = lane >> 4;

    f32x4 acc[4][4];
#pragma unroll
    for (int i = 0; i < 4; ++i)
#pragma unroll
        for (int j = 0; j < 4; ++j) acc[i][j] = (f32x4){0.f, 0.f, 0.f, 0.f};

    const int srow = tid >> 3;
    const int skq  = (tid & 7) << 2;
    const int tdb  = tid >> 3;
    const int tkb  = tid & 7;

    for (int k0 = 0; k0 < LKK; k0 += TK) {
        __syncthreads();
#pragma unroll
        for (int i = 0; i < 4; ++i) {
            const int row = i * 32 + srow;
            const f32x4 va = *(const f32x4*)(Pp + (size_t)row * LKK + k0 + skq);
            unsigned* pa = (unsigned*)&lA[row * LDSS + skq];
            pa[0] = pack_bf16x2(va[0], va[1]);
            pa[1] = pack_bf16x2(va[2], va[3]);
        }
        f32x4 rk[4];
#pragma unroll
        for (int j = 0; j < 4; ++j)
            rk[j] = *(const f32x4*)(Kb + (size_t)(k0 + tkb * 4 + j) * DH + n0 + tdb * 4);
#pragma unroll
        for (int c = 0; c < 4; ++c) {
            unsigned* pb = (unsigned*)&lB[(tdb * 4 + c) * LDSS + tkb * 4];
            pb[0] = pack_bf16x2(rk[0][c], rk[1][c]);
            pb[1] = pack_bf16x2(rk[2][c], rk[3][c]);
        }
        __syncthreads();

        bf16x8 af[4], bfr[4];
#pragma unroll
        for (int i = 0; i < 4; ++i) {
            af[i]  = *(const bf16x8*)&lA[(wm + i * 16 + lrow) * LDSS + quad * 8];
            bfr[i] = *(const bf16x8*)&lB[(wn + i * 16 + lrow) * LDSS + quad * 8];
        }
#pragma unroll
        for (int i = 0; i < 4; ++i)
#pragma unroll
            for (int j = 0; j < 4; ++j)
                acc[i][j] = __builtin_amdgcn_mfma_f32_16x16x32_bf16(af[i], bfr[j], acc[i][j], 0, 0, 0);
    }

    const size_t cb = (size_t)b * LQ * DH;
#pragma unroll
    for (int i = 0; i < 4; ++i) {
#pragma unroll
        for (int r = 0; r < 4; ++r) {
            const int row = q0 + wm + i * 16 + quad * 4 + r;
            const size_t rbase = cb + (size_t)row * DH;
#pragma unroll
            for (int j = 0; j < 4; ++j)
                C[rbase + n0 + wn + j * 16 + lrow] = acc[i][j][r];
        }
    }
}

extern "C" void kernel_launch(void* const* d_in, const int* in_sizes, int n_in,
                              void* d_out, int out_size, void* d_ws, size_t ws_size,
                              hipStream_t stream) {
    const float* Q = (const float*)d_in[0];
    const float* K = (const float*)d_in[1];
    const float* M = (const float*)d_in[2];

    constexpr size_t QEL  = (size_t)BATCH * LQ * DH;    // 16,777,216 (ctx elems)
    constexpr size_t AEL  = (size_t)BATCH * LQ * LKK;   // 33,554,432 (attn elems)
    constexpr size_t KTEL = (size_t)BATCH * DH * LKK;   // 16,777,216

    float* ctx  = (float*)d_out;
    float* attn = ctx + QEL;

    // bf16 Q/K scratch inside the (not-yet-written) ctx region: 2*QEL*2B == QEL*4B.
    unsigned short* Qb = (unsigned short*)ctx;
    unsigned short* Kb = Qb + QEL;

    const bool wsOK = ws_size >= (KTEL + AEL) * sizeof(unsigned short);
    unsigned short* KT = (unsigned short*)d_ws;
    unsigned short* ab = KT + KTEL;

    cvt_kernel<<<dim3(8192), 256, 0, stream>>>(Q, K, Qb, Kb);
    if (wsOK)
        kt_kernel<<<dim3(DH / 64, LKK / 64, BATCH), 256, 0, stream>>>(K, KT);
    qk8<<<dim3(BATCH * (LQ / 256) * (LKK / 256)), 512, 0, stream>>>(Qb, Kb, M, attn);
    softmax_kernel<<<dim3(BATCH * LQ / 4), 256, 0, stream>>>(attn, wsOK ? ab : nullptr);
    if (wsOK)
        pk8<<<dim3(BATCH * (LQ / 256) * (DH / 256)), 512, 0, stream>>>(ab, KT, ctx);
    else
        pk_kernel<<<dim3(DH / BN, LQ / BM, BATCH), 256, 0, stream>>>(attn, K, ctx);
}

// Round 4
// 540.007 us; speedup vs baseline: 1.0642x; 1.0642x over previous
//
#include <hip/hip_runtime.h>
#include <hip/hip_bf16.h>

// S = (Q K^T)/32 * mask (multiplicative), attn = softmax(S), ctx = attn * K.
// d_out = ctx (8*2048*1024 f32) ++ attn (8*2048*2048 f32).
// R6: memory-path restructure. qk8 writes UNNORMALIZED e=exp(S') as bf16 only
// (no f32 S pass); sum_norm reads e-bf16, writes normalized attn f32 + inv[row];
// pk8 consumes e-bf16 and scales by inv[row] in epilogue. kt also emits Kb so
// K f32 is read once. GEMM mainloop unchanged from R5 (best measured).

typedef __attribute__((ext_vector_type(8))) short bf16x8;
typedef __attribute__((ext_vector_type(4))) float f32x4;
typedef __attribute__((ext_vector_type(4))) unsigned u32x4;
typedef __attribute__((ext_vector_type(2))) unsigned u32x2;

constexpr int BATCH = 8;
constexpr int LQ    = 2048;
constexpr int LKK   = 2048;
constexpr int DH    = 1024;
constexpr float SCALE = 0.03125f;   // 1/sqrt(1024)

#define GAS(p) ((const __attribute__((address_space(1))) void*)(p))
#define LAS(p) ((__attribute__((address_space(3))) void*)(p))

// 32-bit LDS byte offset of a generic pointer into __shared__
__device__ __forceinline__ unsigned lds_addr(const unsigned short* p) {
    return (unsigned)(unsigned long long)
        (const __attribute__((address_space(3))) unsigned short*)p;
}

// opaque LDS read (rule 18: caller waits lgkmcnt + sched_barrier(0) before use)
__device__ __forceinline__ bf16x8 dsr_b128(unsigned off) {
    bf16x8 r;
    asm volatile("ds_read_b128 %0, %1" : "=v"(r) : "v"(off));
    return r;
}

// round-half-up fp32->bf16 pair pack (2 adds + v_perm)
__device__ __forceinline__ unsigned pack_bf16x2(float x0, float x1) {
    unsigned a = __builtin_bit_cast(unsigned, x0) + 0x8000u;
    unsigned b = __builtin_bit_cast(unsigned, x1) + 0x8000u;
    return __builtin_amdgcn_perm(b, a, 0x07060302u);  // mem order: x0.hi16, x1.hi16
}

__device__ __forceinline__ unsigned short pack_bf16(float x) {
    return (unsigned short)((__builtin_bit_cast(unsigned, x) + 0x8000u) >> 16);
}

// ---------------- prep: Q (and K if fallback) fp32 -> bf16 ------------------------
__global__ __launch_bounds__(256)
void cvt_kernel(const float* __restrict__ Q, const float* __restrict__ K,
                unsigned short* __restrict__ Qb, unsigned short* __restrict__ Kb) {
    const int bid = blockIdx.x;
    const float* src; unsigned short* dst; size_t off;
    if (bid < 4096) { src = Q; dst = Qb; off = (size_t)bid * 4096; }
    else            { src = K; dst = Kb; off = (size_t)(bid - 4096) * 4096; }
    off += (size_t)threadIdx.x * 16;
    const f32x4 a = *(const f32x4*)(src + off);
    const f32x4 b = *(const f32x4*)(src + off + 4);
    const f32x4 c = *(const f32x4*)(src + off + 8);
    const f32x4 d = *(const f32x4*)(src + off + 12);
    u32x4 v0, v1;
    v0[0] = pack_bf16x2(a[0], a[1]); v0[1] = pack_bf16x2(a[2], a[3]);
    v0[2] = pack_bf16x2(b[0], b[1]); v0[3] = pack_bf16x2(b[2], b[3]);
    v1[0] = pack_bf16x2(c[0], c[1]); v1[1] = pack_bf16x2(c[2], c[3]);
    v1[2] = pack_bf16x2(d[0], d[1]); v1[3] = pack_bf16x2(d[2], d[3]);
    *(u32x4*)(dst + off)     = v0;
    *(u32x4*)(dst + off + 8) = v1;
}

// ---------------- prep: K fp32 -> K^T bf16 (LDS transpose) AND row-major Kb -------
__global__ __launch_bounds__(256)
void kt_kernel(const float* __restrict__ K, unsigned short* __restrict__ KT,
               unsigned short* __restrict__ Kb) {
    __shared__ unsigned short T[64 * 68];
    const int b  = blockIdx.z;
    const int k0 = blockIdx.y * 64;
    const int d0 = blockIdx.x * 64;
    const int t  = threadIdx.x;
    const int k4 = (t >> 4) * 4;
    const int d4 = (t & 15) * 4;
    f32x4 rk[4];
    const float* Kp = K + ((size_t)b * LKK + k0 + k4) * DH + d0 + d4;
#pragma unroll
    for (int j = 0; j < 4; ++j) rk[j] = *(const f32x4*)(Kp + (size_t)j * DH);
    // row-major bf16 copy (16 lanes x 8 B = 128 B contiguous per k-row)
    unsigned short* Kbp = Kb + ((size_t)b * LKK + k0 + k4) * DH + d0 + d4;
#pragma unroll
    for (int j = 0; j < 4; ++j) {
        u32x2 w;
        w[0] = pack_bf16x2(rk[j][0], rk[j][1]);
        w[1] = pack_bf16x2(rk[j][2], rk[j][3]);
        *(u32x2*)(Kbp + (size_t)j * DH) = w;
    }
    // transposed copy via LDS
#pragma unroll
    for (int c = 0; c < 4; ++c) {
        u32x2 w;
        w[0] = pack_bf16x2(rk[0][c], rk[1][c]);
        w[1] = pack_bf16x2(rk[2][c], rk[3][c]);
        *(u32x2*)&T[(d4 + c) * 68 + k4] = w;
    }
    __syncthreads();
    const int d  = t >> 2;
    const int kc = (t & 3) * 16;
    u32x2 a0 = *(const u32x2*)&T[d * 68 + kc];
    u32x2 a1 = *(const u32x2*)&T[d * 68 + kc + 4];
    u32x2 a2 = *(const u32x2*)&T[d * 68 + kc + 8];
    u32x2 a3 = *(const u32x2*)&T[d * 68 + kc + 12];
    unsigned short* dst = KT + ((size_t)b * DH + d0 + d) * LKK + k0 + kc;
    u32x4 w0; w0[0] = a0[0]; w0[1] = a0[1]; w0[2] = a1[0]; w0[3] = a1[1];
    u32x4 w1; w1[0] = a2[0]; w1[1] = a2[1]; w1[2] = a3[0]; w1[3] = a3[1];
    *(u32x4*)dst       = w0;
    *(u32x4*)(dst + 8) = w1;
}

// ================= 256x256 BK=64 pipelined mainloop (R5 schedule) ==================
// (unchanged from R5 — see R5 comments for the WAR/RAW derivation)
template<int LDA, int LDB, int NT>
__device__ __forceinline__ void gemm8_mainloop(
    const unsigned short* __restrict__ Ab,
    const unsigned short* __restrict__ Bb,
    unsigned short* lA, unsigned short* lB,
    f32x4 (&acc)[8][4])
{
    const int tid  = threadIdx.x;
    const int lane = tid & 63;
    const int wid  = tid >> 6;
    const int wm   = (wid & 1) * 128;
    const int wn   = (wid >> 1) * 64;
    const int lrow = lane & 15;
    const int quad = lane >> 4;
    const int slotsw = (quad ^ ((lrow >> 1) & 3)) * 8;

    const int srow0 = wid * 32 + (lane >> 2);
    const int srow1 = srow0 + 16;
    const int sc    = ((lane & 3) ^ ((lane >> 3) & 3)) * 8;

    auto stage = [&](int I) {
        if (I >= 4 * NT) return;
        const int tile = I >> 2;
        const int h    = I & 3;
        const int kh   = h >> 1;
        const int kb   = tile * 64 + kh * 32 + sc;
        const unsigned short* s = (h & 1) ? Bb : Ab;
        const int ld            = (h & 1) ? LDB : LDA;
        unsigned short* d = ((h & 1) ? lB : lA)
                          + (tile & 1) * 16384 + kh * 8192 + wid * 1024;
        __builtin_amdgcn_global_load_lds(GAS(s + (size_t)srow0 * ld + kb), LAS(d),       16, 0, 0);
        __builtin_amdgcn_global_load_lds(GAS(s + (size_t)srow1 * ld + kb), LAS(d + 512), 16, 0, 0);
    };

#pragma unroll
    for (int i = 0; i < 8; ++i)
#pragma unroll
        for (int j = 0; j < 4; ++j) acc[i][j] = (f32x4){0.f, 0.f, 0.f, 0.f};

#pragma unroll
    for (int I = 0; I < 6; ++I) stage(I);
    asm volatile("s_waitcnt vmcnt(8)" ::: "memory");
    __builtin_amdgcn_s_barrier();

    auto tilebody = [&](int T, int par) {
        bf16x8 bfr[4];
#pragma unroll
        for (int q = 0; q < 4; ++q) {
            const int kh = (q >> 1) * 8192;
            const int mh = (q & 1) * 4;
            if ((q & 1) == 0) {
#pragma unroll
                for (int nf = 0; nf < 4; ++nf)
                    bfr[nf] = dsr_b128(lds_addr(&lB[par + kh + (wn + nf * 16 + lrow) * 32 + slotsw]));
            }
            bf16x8 af[4];
#pragma unroll
            for (int mf = 0; mf < 4; ++mf)
                af[mf] = dsr_b128(lds_addr(&lA[par + kh + (wm + (mh + mf) * 16 + lrow) * 32 + slotsw]));

            if (q == 0)      stage(4 * T + 6);
            else if (q == 1) stage(4 * T + 7);
            else if (q == 2) { stage(4 * T + 8); stage(4 * T + 9); }

            __builtin_amdgcn_s_barrier();
            asm volatile("s_waitcnt lgkmcnt(0)" ::: "memory");
            __builtin_amdgcn_sched_barrier(0);
            __builtin_amdgcn_s_setprio(1);
#pragma unroll
            for (int mf = 0; mf < 4; ++mf)
#pragma unroll
                for (int nf = 0; nf < 4; ++nf)
                    acc[mh + mf][nf] = __builtin_amdgcn_mfma_f32_16x16x32_bf16(
                        af[mf], bfr[nf], acc[mh + mf][nf], 0, 0, 0);
            __builtin_amdgcn_s_setprio(0);
            if (q == 1) {
                if (T < NT - 1)       asm volatile("s_waitcnt vmcnt(8)" ::: "memory");
                else                  asm volatile("s_waitcnt vmcnt(0)" ::: "memory");
            } else if (q == 3) {
                if (T < NT - 2)       asm volatile("s_waitcnt vmcnt(8)" ::: "memory");
                else if (T == NT - 2) asm volatile("s_waitcnt vmcnt(4)" ::: "memory");
            }
            __builtin_amdgcn_s_barrier();
        }
    };

    for (int T = 0; T < NT; T += 2) {
        tilebody(T,     0);
        tilebody(T + 1, 16384);
    }
}

// ---------------- GEMM1: FUSED -> ab = bf16(exp(S*SCALE*M)); else S f32 ------------
template<bool FUSED>
__global__ __launch_bounds__(512, 2)
void qk8(const unsigned short* __restrict__ Qb, const unsigned short* __restrict__ Kb,
         const float* __restrict__ M, float* __restrict__ S,
         unsigned short* __restrict__ ab) {
    __shared__ __align__(16) unsigned short lA[32768];
    __shared__ __align__(16) unsigned short lB[32768];

    // 512 blocks: XCD-bijective swizzle (512 % 8 == 0); each XCD chunk = one batch.
    const int l   = blockIdx.x;
    const int swz = (l & 7) * 64 + (l >> 3);
    const int b   = swz >> 6;
    const int my  = (swz >> 3) & 7;
    const int nx  = swz & 7;
    const int q0  = my * 256;
    const int n0  = nx * 256;

    const unsigned short* Ap = Qb + ((size_t)b * LQ  + q0) * DH;
    const unsigned short* Bp = Kb + ((size_t)b * LKK + n0) * DH;

    f32x4 acc[8][4];
    gemm8_mainloop<DH, DH, DH / 64>(Ap, Bp, lA, lB, acc);

    const int lane = threadIdx.x & 63;
    const int wid  = threadIdx.x >> 6;
    const int wm   = (wid & 1) * 128;
    const int wn   = (wid >> 1) * 64;
    const int lrow = lane & 15;
    const int quad = lane >> 4;

    // C/D layout: col = lane&15, row = quad*4 + r (m89/m91)
    const size_t base = (size_t)b * LQ * LKK;
#pragma unroll
    for (int mf = 0; mf < 8; ++mf) {
#pragma unroll
        for (int r = 0; r < 4; ++r) {
            const int row = q0 + wm + mf * 16 + quad * 4 + r;
            const size_t rb = base + (size_t)row * LKK;
#pragma unroll
            for (int nf = 0; nf < 4; ++nf) {
                const int col = n0 + wn + nf * 16 + lrow;
                if (FUSED) {
                    // e = exp(S'); |S'| <= ~6 so exp is f32-safe without max-sub.
                    const float e = __expf(acc[mf][nf][r] * SCALE * M[rb + col]);
                    ab[rb + col] = pack_bf16(e);
                } else {
                    S[rb + col] = acc[mf][nf][r] * SCALE * M[rb + col];
                }
            }
        }
    }
}

// ---------------- sum+normalize: attn = e*inv (f32), inv[row] saved for pk8 --------
__global__ __launch_bounds__(256)
void sum_norm(const unsigned short* __restrict__ ab, float* __restrict__ attn,
              float* __restrict__ inv) {
    const int row  = blockIdx.x * 4 + (threadIdx.x >> 6);
    const int lane = threadIdx.x & 63;
    const unsigned short* q = ab + (size_t)row * LKK;

    u32x4 w[4];
#pragma unroll
    for (int i = 0; i < 4; ++i) w[i] = *(const u32x4*)(q + i * 512 + lane * 8);

    float v[32];
    float s = 0.f;
#pragma unroll
    for (int i = 0; i < 4; ++i)
#pragma unroll
        for (int j = 0; j < 4; ++j) {
            const unsigned u = w[i][j];
            const float lo = __builtin_bit_cast(float, u << 16);
            const float hi = __builtin_bit_cast(float, u & 0xFFFF0000u);
            v[i * 8 + j * 2]     = lo;
            v[i * 8 + j * 2 + 1] = hi;
            s += lo + hi;
        }
#pragma unroll
    for (int o = 32; o >= 1; o >>= 1) s += __shfl_xor(s, o, 64);
    const float iv = 1.f / s;

    float* p = attn + (size_t)row * LKK;
#pragma unroll
    for (int i = 0; i < 4; ++i) {
        f32x4 o0, o1;
#pragma unroll
        for (int j = 0; j < 4; ++j) { o0[j] = v[i * 8 + j] * iv; o1[j] = v[i * 8 + 4 + j] * iv; }
        *(f32x4*)(p + i * 512 + lane * 8)     = o0;
        *(f32x4*)(p + i * 512 + lane * 8 + 4) = o1;
    }
    if (lane == 0) inv[row] = iv;
}

// ---------------- legacy softmax (fallback path): normalize f32 in place ----------
__global__ __launch_bounds__(256)
void softmax_kernel(float* __restrict__ A, unsigned short* __restrict__ ab) {
    const int row  = blockIdx.x * 4 + (threadIdx.x >> 6);
    const int lane = threadIdx.x & 63;
    float* p = A + (size_t)row * LKK;

    f32x4 v[8];
#pragma unroll
    for (int i = 0; i < 8; ++i) v[i] = *(const f32x4*)(p + i * 256 + lane * 4);

    float m = v[0][0];
#pragma unroll
    for (int i = 0; i < 8; ++i)
#pragma unroll
        for (int j = 0; j < 4; ++j) m = fmaxf(m, v[i][j]);
#pragma unroll
    for (int o = 32; o >= 1; o >>= 1) m = fmaxf(m, __shfl_xor(m, o, 64));

    float s = 0.f;
#pragma unroll
    for (int i = 0; i < 8; ++i)
#pragma unroll
        for (int j = 0; j < 4; ++j) { v[i][j] = __expf(v[i][j] - m); s += v[i][j]; }
#pragma unroll
    for (int o = 32; o >= 1; o >>= 1) s += __shfl_xor(s, o, 64);
    const float inv = 1.f / s;

#pragma unroll
    for (int i = 0; i < 8; ++i) {
#pragma unroll
        for (int j = 0; j < 4; ++j) v[i][j] *= inv;
        *(f32x4*)(p + i * 256 + lane * 4) = v[i];
    }

    if (ab) {
        unsigned short* q = ab + (size_t)row * LKK;
#pragma unroll
        for (int i = 0; i < 8; ++i) {
            u32x2 w;
            w[0] = pack_bf16x2(v[i][0], v[i][1]);
            w[1] = pack_bf16x2(v[i][2], v[i][3]);
            *(u32x2*)(q + i * 256 + lane * 4) = w;
        }
    }
}

// ---------------- GEMM2: ctx = (e_bf * KT_bf) * inv[row] ---------------------------
__global__ __launch_bounds__(512, 2)
void pk8(const unsigned short* __restrict__ Pb, const unsigned short* __restrict__ KT,
         const float* __restrict__ Inv, float* __restrict__ C) {
    __shared__ __align__(16) unsigned short lA[32768];
    __shared__ __align__(16) unsigned short lB[32768];

    // 256 blocks: b(8) x my(8) x nx(4), XCD-bijective swizzle (256 % 8 == 0).
    const int l   = blockIdx.x;
    const int swz = (l & 7) * 32 + (l >> 3);
    const int b   = swz >> 5;
    const int my  = (swz >> 2) & 7;
    const int nx  = swz & 3;
    const int q0  = my * 256;
    const int n0  = nx * 256;   // d offset

    const unsigned short* Ap = Pb + ((size_t)b * LQ + q0) * LKK;
    const unsigned short* Bp = KT + ((size_t)b * DH + n0) * LKK;

    f32x4 acc[8][4];
    gemm8_mainloop<LKK, LKK, LKK / 64>(Ap, Bp, lA, lB, acc);

    const int lane = threadIdx.x & 63;
    const int wid  = threadIdx.x >> 6;
    const int wm   = (wid & 1) * 128;
    const int wn   = (wid >> 1) * 64;
    const int lrow = lane & 15;
    const int quad = lane >> 4;

    const float* Ivp = Inv + (size_t)b * LQ;
    const size_t cb = (size_t)b * LQ * DH;
#pragma unroll
    for (int mf = 0; mf < 8; ++mf) {
#pragma unroll
        for (int r = 0; r < 4; ++r) {
            const int row = q0 + wm + mf * 16 + quad * 4 + r;
            const float iv = Ivp[row];
            const size_t rbase = cb + (size_t)row * DH;
#pragma unroll
            for (int nf = 0; nf < 4; ++nf)
                C[rbase + n0 + wn + nf * 16 + lrow] = acc[mf][nf][r] * iv;
        }
    }
}

// ---------------- GEMM2 fallback (128^2 2-phase): inline fp32->bf16 ----------------
constexpr int BM = 128, BN = 128, TK = 32;
constexpr int LDSS = 40;
__global__ __launch_bounds__(256, 2)
void pk_kernel(const float* __restrict__ P, const float* __restrict__ K,
               float* __restrict__ C) {
    __shared__ unsigned short lA[BM * LDSS];
    __shared__ unsigned short lB[BN * LDSS];

    const int b  = blockIdx.z;
    const int q0 = blockIdx.y * BM;
    const int n0 = blockIdx.x * BN;
    const float* Pp = P + (size_t)b * LQ * LKK + (size_t)q0 * LKK;
    const float* Kb = K + (size_t)b * LKK * DH;

    const int tid  = threadIdx.x;
    const int lane = tid & 63;
    const int wid  = tid >> 6;
    const int wm   = (wid & 1) * 64;
    const int wn   = (wid >> 1) * 64;
    const int lrow = lane & 15;
    const int quad = lane >> 4;

    f32x4 acc[4][4];
#pragma unroll
    for (int i = 0; i < 4; ++i)
#pragma unroll
        for (int j = 0; j < 4; ++j) acc[i][j] = (f32x4){0.f, 0.f, 0.f, 0.f};

    const int srow = tid >> 3;
    const int skq  = (tid & 7) << 2;
    const int tdb  = tid >> 3;
    const int tkb  = tid & 7;

    for (int k0 = 0; k0 < LKK; k0 += TK) {
        __syncthreads();
#pragma unroll
        for (int i = 0; i < 4; ++i) {
            const int row = i * 32 + srow;
            const f32x4 va = *(const f32x4*)(Pp + (size_t)row * LKK + k0 + skq);
            unsigned* pa = (unsigned*)&lA[row * LDSS + skq];
            pa[0] = pack_bf16x2(va[0], va[1]);
            pa[1] = pack_bf16x2(va[2], va[3]);
        }
        f32x4 rk[4];
#pragma unroll
        for (int j = 0; j < 4; ++j)
            rk[j] = *(const f32x4*)(Kb + (size_t)(k0 + tkb * 4 + j) * DH + n0 + tdb * 4);
#pragma unroll
        for (int c = 0; c < 4; ++c) {
            unsigned* pb = (unsigned*)&lB[(tdb * 4 + c) * LDSS + tkb * 4];
            pb[0] = pack_bf16x2(rk[0][c], rk[1][c]);
            pb[1] = pack_bf16x2(rk[2][c], rk[3][c]);
        }
        __syncthreads();

        bf16x8 af[4], bfr[4];
#pragma unroll
        for (int i = 0; i < 4; ++i) {
            af[i]  = *(const bf16x8*)&lA[(wm + i * 16 + lrow) * LDSS + quad * 8];
            bfr[i] = *(const bf16x8*)&lB[(wn + i * 16 + lrow) * LDSS + quad * 8];
        }
#pragma unroll
        for (int i = 0; i < 4; ++i)
#pragma unroll
            for (int j = 0; j < 4; ++j)
                acc[i][j] = __builtin_amdgcn_mfma_f32_16x16x32_bf16(af[i], bfr[j], acc[i][j], 0, 0, 0);
    }

    const size_t cb = (size_t)b * LQ * DH;
#pragma unroll
    for (int i = 0; i < 4; ++i) {
#pragma unroll
        for (int r = 0; r < 4; ++r) {
            const int row = q0 + wm + i * 16 + quad * 4 + r;
            const size_t rbase = cb + (size_t)row * DH;
#pragma unroll
            for (int j = 0; j < 4; ++j)
                C[rbase + n0 + wn + j * 16 + lrow] = acc[i][j][r];
        }
    }
}

extern "C" void kernel_launch(void* const* d_in, const int* in_sizes, int n_in,
                              void* d_out, int out_size, void* d_ws, size_t ws_size,
                              hipStream_t stream) {
    const float* Q = (const float*)d_in[0];
    const float* K = (const float*)d_in[1];
    const float* M = (const float*)d_in[2];

    constexpr size_t QEL  = (size_t)BATCH * LQ * DH;    // 16,777,216 (ctx elems)
    constexpr size_t AEL  = (size_t)BATCH * LQ * LKK;   // 33,554,432 (attn elems)
    constexpr size_t KTEL = (size_t)BATCH * DH * LKK;   // 16,777,216
    constexpr size_t REL  = (size_t)BATCH * LQ;         // 16,384 row sums

    float* ctx  = (float*)d_out;
    float* attn = ctx + QEL;

    // bf16 Q/K scratch inside the (not-yet-written) ctx region: 2*QEL*2B == QEL*4B.
    unsigned short* Qb = (unsigned short*)ctx;
    unsigned short* Kb = Qb + QEL;

    const bool wsOK = ws_size >= (KTEL + AEL) * sizeof(unsigned short)
                               + REL * sizeof(float);
    unsigned short* KT = (unsigned short*)d_ws;
    unsigned short* ab = KT + KTEL;
    float* inv = (float*)(ab + AEL);

    if (wsOK) {
        cvt_kernel<<<dim3(4096), 256, 0, stream>>>(Q, K, Qb, Kb);   // Q only
        kt_kernel<<<dim3(DH / 64, LKK / 64, BATCH), 256, 0, stream>>>(K, KT, Kb);
        qk8<true><<<dim3(BATCH * (LQ / 256) * (LKK / 256)), 512, 0, stream>>>(
            Qb, Kb, M, nullptr, ab);
        sum_norm<<<dim3(BATCH * LQ / 4), 256, 0, stream>>>(ab, attn, inv);
        pk8<<<dim3(BATCH * (LQ / 256) * (DH / 256)), 512, 0, stream>>>(ab, KT, inv, ctx);
    } else {
        cvt_kernel<<<dim3(8192), 256, 0, stream>>>(Q, K, Qb, Kb);   // Q and K
        qk8<false><<<dim3(BATCH * (LQ / 256) * (LKK / 256)), 512, 0, stream>>>(
            Qb, Kb, M, attn, nullptr);
        softmax_kernel<<<dim3(BATCH * LQ / 4), 256, 0, stream>>>(attn, nullptr);
        pk_kernel<<<dim3(DH / BN, LQ / BM, BATCH), 256, 0, stream>>>(attn, K, ctx);
    }
}